// Round 5
// baseline (62.847 us; speedup 1.0000x reference)
//
#include <hip/hip_runtime.h>
#include <math.h>

#define NAG 64
#define ZD  512
#define DM  512
#define KT  64          // columns per tile
#define NT  (ZD / KT)   // 8 tiles
#define RPB 128         // rows per block

// ---------------------------------------------------------------------------
// global -> LDS async DMA, 16 bytes per lane. LDS dest must be the
// wave-uniform base (HW adds lane*16); global src is per-lane.
// ---------------------------------------------------------------------------
__device__ __forceinline__ void gload_lds16(const float* g, float* l)
{
    __builtin_amdgcn_global_load_lds(
        (const __attribute__((address_space(1))) unsigned int*)g,
        (__attribute__((address_space(3))) unsigned int*)l,
        16, 0, 0);
}

// ---------------------------------------------------------------------------
// Kernel A: batched per-agent GEMV for Q,K,V via LDS-staged streaming.
// 768 blocks x 128 threads. Block b owns 128 consecutive rows of the
// flattened [3*64*512] row space (one matrix, one agent). K dim split into
// 8 tiles of 64 cols; tiles staged by global_load_lds into a double buffer.
// Thread r owns one output row: serial in-register accumulation, no shfl.
// LDS tile layout: Wt[row][64] floats; slot s (float4 #s) of row r holds
// global col-slot (s - r) & 15  (inverse-swizzled source, linear dest);
// reader uses slot (j + r) & 15 to fetch global slot j -> 8-way banks max.
// ---------------------------------------------------------------------------
__global__ __launch_bounds__(128) void qkv_gemv_kernel(
    const float* __restrict__ z,
    const float* __restrict__ Wq,
    const float* __restrict__ Wk,
    const float* __restrict__ Wv,
    float* __restrict__ Q, float* __restrict__ K, float* __restrict__ V)
{
    __shared__ __align__(16) float Wt[2][RPB * KT];   // 2 x 32 KB

    const int tid  = threadIdx.x;
    const int wv   = tid >> 6;
    const int lane = tid & 63;

    const int R0 = blockIdx.x * RPB;        // flattened row base
    const int m  = R0 >> 15;                // matrix select (32768 rows each)
    const int n  = (R0 >> 9) & 63;          // agent
    const int d0 = R0 & 511;                // row offset within agent matrix

    const float* __restrict__ Wm = ((m == 0) ? Wq : (m == 1) ? Wk : Wv)
                                   + ((size_t)(n * DM + d0)) * ZD;
    float* __restrict__ O        = ((m == 0) ? Q : (m == 1) ? K : V)
                                   + n * DM + d0;
    const float* __restrict__ zn = z + n * ZD;   // block-uniform reads

    // per-lane staging geometry (constant across tiles)
    const int srow  = wv * 64 + (lane >> 4);     // row this lane feeds (per instr i: +4*i)
    const int sslot = lane & 15;

    // ---- stage tile 0 ----
#pragma unroll
    for (int i = 0; i < 16; ++i) {
        const int row   = srow + i * 4;
        const int gslot = (sslot - row) & 15;
        gload_lds16(Wm + (size_t)row * ZD + gslot * 4,
                    &Wt[0][(wv * 64 + i * 4) * KT]);
    }
    __syncthreads();   // drains vmcnt -> tile 0 resident

    const int r = tid;                       // output row owned by this thread
    float a0 = 0.f, a1 = 0.f, a2 = 0.f, a3 = 0.f;
    int buf = 0;

#pragma unroll
    for (int t = 0; t < NT; ++t) {
        // stage tile t+1 into the other buffer (DMA overlaps compute below)
        if (t + 1 < NT) {
            const int k0n = (t + 1) * KT;
#pragma unroll
            for (int i = 0; i < 16; ++i) {
                const int row   = srow + i * 4;
                const int gslot = (sslot - row) & 15;
                gload_lds16(Wm + (size_t)row * ZD + k0n + gslot * 4,
                            &Wt[buf ^ 1][(wv * 64 + i * 4) * KT]);
            }
        }
        // compute tile t from LDS
        const int k0 = t * KT;
        const float* wrow = &Wt[buf][r * KT];
#pragma unroll
        for (int j = 0; j < 16; j += 4) {
            const int s0 = (j + 0 + r) & 15;
            const int s1 = (j + 1 + r) & 15;
            const int s2 = (j + 2 + r) & 15;
            const int s3 = (j + 3 + r) & 15;
            const float4 w0 = *reinterpret_cast<const float4*>(wrow + s0 * 4);
            const float4 w1 = *reinterpret_cast<const float4*>(wrow + s1 * 4);
            const float4 w2 = *reinterpret_cast<const float4*>(wrow + s2 * 4);
            const float4 w3 = *reinterpret_cast<const float4*>(wrow + s3 * 4);
            const float4 z0 = *reinterpret_cast<const float4*>(zn + k0 + (j + 0) * 4);
            const float4 z1 = *reinterpret_cast<const float4*>(zn + k0 + (j + 1) * 4);
            const float4 z2 = *reinterpret_cast<const float4*>(zn + k0 + (j + 2) * 4);
            const float4 z3 = *reinterpret_cast<const float4*>(zn + k0 + (j + 3) * 4);
            a0 += w0.x*z0.x + w0.y*z0.y + w0.z*z0.z + w0.w*z0.w;
            a1 += w1.x*z1.x + w1.y*z1.y + w1.z*z1.z + w1.w*z1.w;
            a2 += w2.x*z2.x + w2.y*z2.y + w2.z*z2.z + w2.w*z2.w;
            a3 += w3.x*z3.x + w3.y*z3.y + w3.z*z3.z + w3.w*z3.w;
        }
        __syncthreads();   // waits tile t+1 DMA + protects buf reuse
        buf ^= 1;
    }

    O[r] = a0 + a1 + a2 + a3;               // 128 consecutive floats, coalesced
}

// ---------------------------------------------------------------------------
// Kernel B+C fused: blocks [0,64) attention+messages for receiver j;
// blocks [64,576) infer-loss partial for output-dim zp = blk-64.
// ---------------------------------------------------------------------------
__global__ __launch_bounds__(256) void attn_infer_kernel(
    const float* __restrict__ Q, const float* __restrict__ K,
    const float* __restrict__ V, const float* __restrict__ Wi,
    const float* __restrict__ bi, const float* __restrict__ z,
    float* __restrict__ out, float* __restrict__ zp_partial)
{
    __shared__ __align__(16) float sbuf[DM];
    __shared__ float Sc[NAG];
    __shared__ float Al[NAG];
    const int t = threadIdx.x;

    if (blockIdx.x < NAG) {
        const int j = blockIdx.x;
        sbuf[t]       = Q[j * DM + t];
        sbuf[t + 256] = Q[j * DM + t + 256];
        __syncthreads();

        const int i = t >> 2;
        const int c = t & 3;
        const float* Krow = K + i * DM + c * 128;
        const float* Qsub = sbuf + c * 128;
        float p = 0.f;
#pragma unroll
        for (int k = 0; k < 32; ++k) {
            float4 kv = *reinterpret_cast<const float4*>(Krow + k * 4);
            float4 qv = *reinterpret_cast<const float4*>(Qsub + k * 4);
            p += kv.x*qv.x + kv.y*qv.y + kv.z*qv.z + kv.w*qv.w;
        }
        p += __shfl_xor(p, 1);
        p += __shfl_xor(p, 2);
        if (c == 0)
            Sc[i] = (i == j) ? -INFINITY : p * 0.044194173824159216f; // 1/sqrt(512)
        __syncthreads();

        if (t < 64) {
            float s = Sc[t];
            float mx = s;
#pragma unroll
            for (int off = 32; off > 0; off >>= 1) mx = fmaxf(mx, __shfl_xor(mx, off));
            float e = expf(s - mx);           // exp(-inf)=0 masks diagonal
            float sum = e;
#pragma unroll
            for (int off = 32; off > 0; off >>= 1) sum += __shfl_xor(sum, off);
            Al[t] = e / sum;
        }
        __syncthreads();

#pragma unroll
        for (int dd = 0; dd < 2; ++dd) {
            const int d = t + dd * 256;
            float acc = 0.f;
            for (int i2 = 0; i2 < NAG; ++i2) acc += Al[i2] * V[i2 * DM + d];
            out[j * DM + d] = acc;
        }
    } else {
        const int zp = blockIdx.x - NAG;
        const float* wr = Wi + (size_t)zp * DM;
        sbuf[t]       = wr[t];
        sbuf[t + 256] = wr[t + 256];
        __syncthreads();

        const int i = t >> 2;
        const int c = t & 3;
        const float* Vrow = V + i * DM + c * 128;
        const float* Wsub = sbuf + c * 128;
        float p = 0.f;
#pragma unroll
        for (int k = 0; k < 32; ++k) {
            float4 vv = *reinterpret_cast<const float4*>(Vrow + k * 4);
            float4 wv = *reinterpret_cast<const float4*>(Wsub + k * 4);
            p += vv.x*wv.x + vv.y*wv.y + vv.z*wv.z + vv.w*wv.w;
        }
        p += __shfl_xor(p, 1);
        p += __shfl_xor(p, 2);

        float e2 = 0.f;
        if (c == 0) {
            float e = p + bi[zp] - z[i * ZD + zp];
            e2 = e * e;
        }
#pragma unroll
        for (int off = 32; off > 0; off >>= 1) e2 += __shfl_down(e2, off);

        const int wv2 = t >> 6;
        const int ln  = t & 63;
        if (ln == 0) Sc[wv2] = e2;
        __syncthreads();
        if (t == 0) zp_partial[zp] = Sc[0] + Sc[1] + Sc[2] + Sc[3];
    }
}

// ---------------------------------------------------------------------------
// Kernel D: fold the 512 per-zp partials into the scalar loss.
// ---------------------------------------------------------------------------
__global__ __launch_bounds__(64) void loss_reduce_kernel(
    const float* __restrict__ zp_partial, float* __restrict__ out)
{
    float v = 0.f;
#pragma unroll
    for (int k = 0; k < 8; ++k) v += zp_partial[threadIdx.x + k * 64];
#pragma unroll
    for (int off = 32; off > 0; off >>= 1) v += __shfl_down(v, off);
    if (threadIdx.x == 0) out[NAG * DM] = v * (1.0f / (NAG * ZD));
}

extern "C" void kernel_launch(void* const* d_in, const int* in_sizes, int n_in,
                              void* d_out, int out_size, void* d_ws, size_t ws_size,
                              hipStream_t stream) {
    const float* z  = (const float*)d_in[0];
    const float* Wq = (const float*)d_in[1];
    const float* Wk = (const float*)d_in[2];
    const float* Wv = (const float*)d_in[3];
    const float* Wi = (const float*)d_in[4];
    const float* bi = (const float*)d_in[5];
    float* out = (float*)d_out;

    float* Q = (float*)d_ws;
    float* K = Q + NAG * DM;
    float* V = K + NAG * DM;
    float* partial = V + NAG * DM;   // 512 floats

    // 98304 rows / 128 rows per block = 768 blocks
    hipLaunchKernelGGL(qkv_gemv_kernel, dim3(768), dim3(128), 0, stream,
                       z, Wq, Wk, Wv, Q, K, V);
    hipLaunchKernelGGL(attn_infer_kernel, dim3(NAG + ZD), dim3(256), 0, stream,
                       Q, K, V, Wi, bi, z, out, partial);
    hipLaunchKernelGGL(loss_reduce_kernel, dim3(1), dim3(64), 0, stream,
                       partial, out);
}

// Round 6
// 56.504 us; speedup vs baseline: 1.1123x; 1.1123x over previous
//
#include <hip/hip_runtime.h>
#include <math.h>

#define NAG 64
#define ZD  512
#define DM  512

// ---------------------------------------------------------------------------
// Kernel A: batched per-agent GEMV for Q, K, V.
// 768 blocks x 4 waves; each wave owns 32 contiguous rows of ONE
// (matrix, agent) pair -> z fragments loaded once per wave. 8 groups of
// 4 rows, 2-deep register prefetch: group g+1's 8 float4 loads are issued,
// then sched_barrier(0) pins them BEFORE group g's compute, forcing the
// results to stay live (counted vmcnt, ~8 loads in flight per wave).
// __launch_bounds__(256,3) gives regalloc ~170 VGPRs so the prefetch fits.
// ---------------------------------------------------------------------------
__device__ __forceinline__ float dot8(float4 wa, float4 wb, float4 za, float4 zb)
{
    return wa.x*za.x + wa.y*za.y + wa.z*za.z + wa.w*za.w
         + wb.x*zb.x + wb.y*zb.y + wb.z*zb.z + wb.w*zb.w;
}

#define LDG4(dst, ptr) dst = *reinterpret_cast<const float4*>(ptr)

__global__ __launch_bounds__(256, 3) void qkv_gemv_kernel(
    const float* __restrict__ z,
    const float* __restrict__ Wq,
    const float* __restrict__ Wk,
    const float* __restrict__ Wv,
    float* __restrict__ Q, float* __restrict__ K, float* __restrict__ V)
{
    const int wave = threadIdx.x >> 6;
    const int lane = threadIdx.x & 63;
    const int gw   = blockIdx.x * 4 + wave;   // 0..3071
    const int rb   = gw * 32;                 // 32 rows per wave, one (m,n)
    const int m    = rb >> 15;                // matrix select
    const int n    = (rb >> 9) & 63;          // agent
    const int d0   = rb & 511;                // row offset (multiple of 32)

    const float* __restrict__ Wm = ((m == 0) ? Wq : (m == 1) ? Wk : Wv)
                                   + ((size_t)(n * DM + d0)) * ZD;
    float* __restrict__ O        = ((m == 0) ? Q : (m == 1) ? K : V)
                                   + n * DM + d0;
    const float* __restrict__ zn = z + n * ZD;

    const int lo = lane * 4;                  // this lane's column offsets
    const int hi = 256 + lane * 4;

    const float4 za = *reinterpret_cast<const float4*>(zn + lo);
    const float4 zb = *reinterpret_cast<const float4*>(zn + hi);

    // ---- load group 0 ----
    float4 c0, c1, c2, c3, c4, c5, c6, c7;
    {
        const float* b = Wm;
        LDG4(c0, b + lo);            LDG4(c1, b + hi);
        LDG4(c2, b + ZD + lo);       LDG4(c3, b + ZD + hi);
        LDG4(c4, b + 2 * ZD + lo);   LDG4(c5, b + 2 * ZD + hi);
        LDG4(c6, b + 3 * ZD + lo);   LDG4(c7, b + 3 * ZD + hi);
    }

#pragma unroll
    for (int g = 0; g < 8; ++g) {
        float4 n0, n1, n2, n3, n4, n5, n6, n7;
        if (g < 7) {                 // issue group g+1's loads
            const float* b = Wm + (size_t)(g + 1) * 4 * ZD;
            LDG4(n0, b + lo);            LDG4(n1, b + hi);
            LDG4(n2, b + ZD + lo);       LDG4(n3, b + ZD + hi);
            LDG4(n4, b + 2 * ZD + lo);   LDG4(n5, b + 2 * ZD + hi);
            LDG4(n6, b + 3 * ZD + lo);   LDG4(n7, b + 3 * ZD + hi);
        }
        __builtin_amdgcn_sched_barrier(0);   // loads stay issued above compute

        float a0 = dot8(c0, c1, za, zb);
        float a1 = dot8(c2, c3, za, zb);
        float a2 = dot8(c4, c5, za, zb);
        float a3 = dot8(c6, c7, za, zb);
#pragma unroll
        for (int off = 32; off > 0; off >>= 1) {
            a0 += __shfl_down(a0, off);
            a1 += __shfl_down(a1, off);
            a2 += __shfl_down(a2, off);
            a3 += __shfl_down(a3, off);
        }
        if (lane == 0)
            *reinterpret_cast<float4*>(O + g * 4) = make_float4(a0, a1, a2, a3);

        if (g < 7) {
            c0 = n0; c1 = n1; c2 = n2; c3 = n3;
            c4 = n4; c5 = n5; c6 = n6; c7 = n7;
        }
    }
}

// ---------------------------------------------------------------------------
// Kernel B+C fused: blocks [0,64) attention+messages for receiver j;
// blocks [64,576) infer-loss partial for output-dim zp = blk-64.
// ---------------------------------------------------------------------------
__global__ __launch_bounds__(256) void attn_infer_kernel(
    const float* __restrict__ Q, const float* __restrict__ K,
    const float* __restrict__ V, const float* __restrict__ Wi,
    const float* __restrict__ bi, const float* __restrict__ z,
    float* __restrict__ out, float* __restrict__ zp_partial)
{
    __shared__ __align__(16) float sbuf[DM];
    __shared__ float Sc[NAG];
    __shared__ float Al[NAG];
    const int t = threadIdx.x;

    if (blockIdx.x < NAG) {
        const int j = blockIdx.x;
        sbuf[t]       = Q[j * DM + t];
        sbuf[t + 256] = Q[j * DM + t + 256];
        __syncthreads();

        const int i = t >> 2;
        const int c = t & 3;
        const float* Krow = K + i * DM + c * 128;
        const float* Qsub = sbuf + c * 128;
        float p = 0.f;
#pragma unroll
        for (int k = 0; k < 32; ++k) {
            float4 kv = *reinterpret_cast<const float4*>(Krow + k * 4);
            float4 qv = *reinterpret_cast<const float4*>(Qsub + k * 4);
            p += kv.x*qv.x + kv.y*qv.y + kv.z*qv.z + kv.w*qv.w;
        }
        p += __shfl_xor(p, 1);
        p += __shfl_xor(p, 2);
        if (c == 0)
            Sc[i] = (i == j) ? -INFINITY : p * 0.044194173824159216f; // 1/sqrt(512)
        __syncthreads();

        if (t < 64) {
            float s = Sc[t];
            float mx = s;
#pragma unroll
            for (int off = 32; off > 0; off >>= 1) mx = fmaxf(mx, __shfl_xor(mx, off));
            float e = expf(s - mx);           // exp(-inf)=0 masks diagonal
            float sum = e;
#pragma unroll
            for (int off = 32; off > 0; off >>= 1) sum += __shfl_xor(sum, off);
            Al[t] = e / sum;
        }
        __syncthreads();

#pragma unroll
        for (int dd = 0; dd < 2; ++dd) {
            const int d = t + dd * 256;
            float acc = 0.f;
            for (int i2 = 0; i2 < NAG; ++i2) acc += Al[i2] * V[i2 * DM + d];
            out[j * DM + d] = acc;
        }
    } else {
        const int zp = blockIdx.x - NAG;
        const float* wr = Wi + (size_t)zp * DM;
        sbuf[t]       = wr[t];
        sbuf[t + 256] = wr[t + 256];
        __syncthreads();

        const int i = t >> 2;
        const int c = t & 3;
        const float* Vrow = V + i * DM + c * 128;
        const float* Wsub = sbuf + c * 128;
        float p = 0.f;
#pragma unroll
        for (int k = 0; k < 32; ++k) {
            float4 vv = *reinterpret_cast<const float4*>(Vrow + k * 4);
            float4 wv = *reinterpret_cast<const float4*>(Wsub + k * 4);
            p += vv.x*wv.x + vv.y*wv.y + vv.z*wv.z + vv.w*wv.w;
        }
        p += __shfl_xor(p, 1);
        p += __shfl_xor(p, 2);

        float e2 = 0.f;
        if (c == 0) {
            float e = p + bi[zp] - z[i * ZD + zp];
            e2 = e * e;
        }
#pragma unroll
        for (int off = 32; off > 0; off >>= 1) e2 += __shfl_down(e2, off);

        const int wv2 = t >> 6;
        const int ln  = t & 63;
        if (ln == 0) Sc[wv2] = e2;
        __syncthreads();
        if (t == 0) zp_partial[zp] = Sc[0] + Sc[1] + Sc[2] + Sc[3];
    }
}

// ---------------------------------------------------------------------------
// Kernel D: fold the 512 per-zp partials into the scalar loss.
// ---------------------------------------------------------------------------
__global__ __launch_bounds__(64) void loss_reduce_kernel(
    const float* __restrict__ zp_partial, float* __restrict__ out)
{
    float v = 0.f;
#pragma unroll
    for (int k = 0; k < 8; ++k) v += zp_partial[threadIdx.x + k * 64];
#pragma unroll
    for (int off = 32; off > 0; off >>= 1) v += __shfl_down(v, off);
    if (threadIdx.x == 0) out[NAG * DM] = v * (1.0f / (NAG * ZD));
}

extern "C" void kernel_launch(void* const* d_in, const int* in_sizes, int n_in,
                              void* d_out, int out_size, void* d_ws, size_t ws_size,
                              hipStream_t stream) {
    const float* z  = (const float*)d_in[0];
    const float* Wq = (const float*)d_in[1];
    const float* Wk = (const float*)d_in[2];
    const float* Wv = (const float*)d_in[3];
    const float* Wi = (const float*)d_in[4];
    const float* bi = (const float*)d_in[5];
    float* out = (float*)d_out;

    float* Q = (float*)d_ws;
    float* K = Q + NAG * DM;
    float* V = K + NAG * DM;
    float* partial = V + NAG * DM;   // 512 floats

    // 98304 rows / (4 waves * 32 rows) = 768 blocks
    hipLaunchKernelGGL(qkv_gemv_kernel, dim3(768), dim3(256), 0, stream,
                       z, Wq, Wk, Wv, Q, K, V);
    hipLaunchKernelGGL(attn_infer_kernel, dim3(NAG + ZD), dim3(256), 0, stream,
                       Q, K, V, Wi, bi, z, out, partial);
    hipLaunchKernelGGL(loss_reduce_kernel, dim3(1), dim3(64), 0, stream,
                       partial, out);
}

// Round 7
// 53.695 us; speedup vs baseline: 1.1704x; 1.0523x over previous
//
#include <hip/hip_runtime.h>
#include <math.h>

#define NAG 64
#define ZD  512
#define DM  512

typedef float f32x4 __attribute__((ext_vector_type(4)));

// ---------------------------------------------------------------------------
// asm global loads: 16B per lane, immediate byte offset. volatile => the
// compiler cannot merge, reorder, or collapse the pipeline (rounds 2-6 all
// lost to the scheduler at C level; VGPR_Count 28-56 proved the prefetch
// never stayed live). vmcnt is managed BY HAND below.
// ---------------------------------------------------------------------------
#define GLD(d, b, OFF) \
    asm volatile("global_load_dwordx4 %0, %1, off offset:" OFF \
                 : "=v"(d) : "v"(b))

// wait until at most N vector-memory ops outstanding, then fence the
// scheduler so dependent VALU can't hoist above the wait (rule #18).
#define VWAIT(N) do { \
    asm volatile("s_waitcnt vmcnt(" #N ")" ::: "memory"); \
    __builtin_amdgcn_sched_barrier(0); \
} while (0)

// issue one group: 4 rows x 2 halves. base = row0 of group + lane*4 floats.
// rows are 2048 B apart; halves 1024 B apart; all offsets <= 3072 (13-bit ok).
#define ISSUE(P, base) do { \
    const float* _bA = (base); \
    const float* _bC = _bA + 2 * ZD; \
    GLD(P##0, _bA, "0");    GLD(P##1, _bA, "1024"); \
    GLD(P##2, _bA, "2048"); GLD(P##3, _bA, "3072"); \
    GLD(P##4, _bC, "0");    GLD(P##5, _bC, "1024"); \
    GLD(P##6, _bC, "2048"); GLD(P##7, _bC, "3072"); \
} while (0)

__device__ __forceinline__ float dot8v(f32x4 wa, f32x4 wb, f32x4 za, f32x4 zb)
{
    return wa[0]*za[0] + wa[1]*za[1] + wa[2]*za[2] + wa[3]*za[3]
         + wb[0]*zb[0] + wb[1]*zb[1] + wb[2]*zb[2] + wb[3]*zb[3];
}

// compute 4 rows of group P, butterfly-reduce (4 chains interleave), store.
#define COMPUTE(P, g) do { \
    float a0 = dot8v(P##0, P##1, zA, zB); \
    float a1 = dot8v(P##2, P##3, zA, zB); \
    float a2 = dot8v(P##4, P##5, zA, zB); \
    float a3 = dot8v(P##6, P##7, zA, zB); \
    _Pragma("unroll") \
    for (int off = 32; off > 0; off >>= 1) { \
        a0 += __shfl_down(a0, off); \
        a1 += __shfl_down(a1, off); \
        a2 += __shfl_down(a2, off); \
        a3 += __shfl_down(a3, off); \
    } \
    if (lane == 0) \
        *reinterpret_cast<float4*>(O + (g) * 4) = make_float4(a0, a1, a2, a3); \
} while (0)

// ---------------------------------------------------------------------------
// Kernel A: batched per-agent GEMV for Q, K, V — hand-pipelined VMEM.
// 768 blocks x 4 waves; wave owns 32 contiguous rows of one (matrix, agent).
// 8 groups of 4 rows; groups g+1 and g+2 are always in flight while g
// computes (16 outstanding loads/wave, vmcnt(8) per step, drain only at end).
// ---------------------------------------------------------------------------
__global__ __launch_bounds__(256, 3) void qkv_gemv_kernel(
    const float* __restrict__ z,
    const float* __restrict__ Wq,
    const float* __restrict__ Wk,
    const float* __restrict__ Wv,
    float* __restrict__ Q, float* __restrict__ K, float* __restrict__ V)
{
    const int wave = threadIdx.x >> 6;
    const int lane = threadIdx.x & 63;
    const int gw   = blockIdx.x * 4 + wave;   // 0..3071
    const int rb   = gw * 32;                 // 32 rows per wave, one (m,n)
    const int m    = rb >> 15;                // matrix select
    const int n    = (rb >> 9) & 63;          // agent
    const int d0   = rb & 511;                // row offset (multiple of 32)

    const float* __restrict__ Wm = ((m == 0) ? Wq : (m == 1) ? Wk : Wv)
                                   + ((size_t)(n * DM + d0)) * ZD;
    float* __restrict__ O        = ((m == 0) ? Q : (m == 1) ? K : V)
                                   + n * DM + d0;
    const float* __restrict__ zn = z + n * ZD;

    const float* lp = Wm + lane * 4;          // lane's column within row 0
    const float* zp = zn + lane * 4;

    f32x4 zA, zB;
    f32x4 A0, A1, A2, A3, A4, A5, A6, A7;
    f32x4 B0, B1, B2, B3, B4, B5, B6, B7;

    // prologue: z (oldest) + groups 0,1  -> 18 outstanding
    GLD(zA, zp, "0");
    GLD(zB, zp, "1024");
    ISSUE(A, lp);                  // group 0
    ISSUE(B, lp + 4 * ZD);         // group 1

    VWAIT(8);  COMPUTE(A, 0);  ISSUE(A, lp +  8 * ZD);   // g2
    VWAIT(8);  COMPUTE(B, 1);  ISSUE(B, lp + 12 * ZD);   // g3
    VWAIT(8);  COMPUTE(A, 2);  ISSUE(A, lp + 16 * ZD);   // g4
    VWAIT(8);  COMPUTE(B, 3);  ISSUE(B, lp + 20 * ZD);   // g5
    VWAIT(8);  COMPUTE(A, 4);  ISSUE(A, lp + 24 * ZD);   // g6
    VWAIT(8);  COMPUTE(B, 5);  ISSUE(B, lp + 28 * ZD);   // g7
    VWAIT(8);  COMPUTE(A, 6);
    VWAIT(0);  COMPUTE(B, 7);
}

// ---------------------------------------------------------------------------
// Kernel B+C fused: blocks [0,64) attention+messages for receiver j;
// blocks [64,576) infer-loss partial for output-dim zp = blk-64.
// ---------------------------------------------------------------------------
__global__ __launch_bounds__(256) void attn_infer_kernel(
    const float* __restrict__ Q, const float* __restrict__ K,
    const float* __restrict__ V, const float* __restrict__ Wi,
    const float* __restrict__ bi, const float* __restrict__ z,
    float* __restrict__ out, float* __restrict__ zp_partial)
{
    __shared__ __align__(16) float sbuf[DM];
    __shared__ float Sc[NAG];
    __shared__ float Al[NAG];
    const int t = threadIdx.x;

    if (blockIdx.x < NAG) {
        const int j = blockIdx.x;
        sbuf[t]       = Q[j * DM + t];
        sbuf[t + 256] = Q[j * DM + t + 256];
        __syncthreads();

        const int i = t >> 2;
        const int c = t & 3;
        const float* Krow = K + i * DM + c * 128;
        const float* Qsub = sbuf + c * 128;
        float p = 0.f;
#pragma unroll
        for (int k = 0; k < 32; ++k) {
            float4 kv = *reinterpret_cast<const float4*>(Krow + k * 4);
            float4 qv = *reinterpret_cast<const float4*>(Qsub + k * 4);
            p += kv.x*qv.x + kv.y*qv.y + kv.z*qv.z + kv.w*qv.w;
        }
        p += __shfl_xor(p, 1);
        p += __shfl_xor(p, 2);
        if (c == 0)
            Sc[i] = (i == j) ? -INFINITY : p * 0.044194173824159216f; // 1/sqrt(512)
        __syncthreads();

        if (t < 64) {
            float s = Sc[t];
            float mx = s;
#pragma unroll
            for (int off = 32; off > 0; off >>= 1) mx = fmaxf(mx, __shfl_xor(mx, off));
            float e = expf(s - mx);           // exp(-inf)=0 masks diagonal
            float sum = e;
#pragma unroll
            for (int off = 32; off > 0; off >>= 1) sum += __shfl_xor(sum, off);
            Al[t] = e / sum;
        }
        __syncthreads();

#pragma unroll
        for (int dd = 0; dd < 2; ++dd) {
            const int d = t + dd * 256;
            float acc = 0.f;
            for (int i2 = 0; i2 < NAG; ++i2) acc += Al[i2] * V[i2 * DM + d];
            out[j * DM + d] = acc;
        }
    } else {
        const int zp = blockIdx.x - NAG;
        const float* wr = Wi + (size_t)zp * DM;
        sbuf[t]       = wr[t];
        sbuf[t + 256] = wr[t + 256];
        __syncthreads();

        const int i = t >> 2;
        const int c = t & 3;
        const float* Vrow = V + i * DM + c * 128;
        const float* Wsub = sbuf + c * 128;
        float p = 0.f;
#pragma unroll
        for (int k = 0; k < 32; ++k) {
            float4 vv = *reinterpret_cast<const float4*>(Vrow + k * 4);
            float4 wv = *reinterpret_cast<const float4*>(Wsub + k * 4);
            p += vv.x*wv.x + vv.y*wv.y + vv.z*wv.z + vv.w*wv.w;
        }
        p += __shfl_xor(p, 1);
        p += __shfl_xor(p, 2);

        float e2 = 0.f;
        if (c == 0) {
            float e = p + bi[zp] - z[i * ZD + zp];
            e2 = e * e;
        }
#pragma unroll
        for (int off = 32; off > 0; off >>= 1) e2 += __shfl_down(e2, off);

        const int wv2 = t >> 6;
        const int ln  = t & 63;
        if (ln == 0) Sc[wv2] = e2;
        __syncthreads();
        if (t == 0) zp_partial[zp] = Sc[0] + Sc[1] + Sc[2] + Sc[3];
    }
}

// ---------------------------------------------------------------------------
// Kernel D: fold the 512 per-zp partials into the scalar loss.
// ---------------------------------------------------------------------------
__global__ __launch_bounds__(64) void loss_reduce_kernel(
    const float* __restrict__ zp_partial, float* __restrict__ out)
{
    float v = 0.f;
#pragma unroll
    for (int k = 0; k < 8; ++k) v += zp_partial[threadIdx.x + k * 64];
#pragma unroll
    for (int off = 32; off > 0; off >>= 1) v += __shfl_down(v, off);
    if (threadIdx.x == 0) out[NAG * DM] = v * (1.0f / (NAG * ZD));
}

extern "C" void kernel_launch(void* const* d_in, const int* in_sizes, int n_in,
                              void* d_out, int out_size, void* d_ws, size_t ws_size,
                              hipStream_t stream) {
    const float* z  = (const float*)d_in[0];
    const float* Wq = (const float*)d_in[1];
    const float* Wk = (const float*)d_in[2];
    const float* Wv = (const float*)d_in[3];
    const float* Wi = (const float*)d_in[4];
    const float* bi = (const float*)d_in[5];
    float* out = (float*)d_out;

    float* Q = (float*)d_ws;
    float* K = Q + NAG * DM;
    float* V = K + NAG * DM;
    float* partial = V + NAG * DM;   // 512 floats

    // 98304 rows / (4 waves * 32 rows) = 768 blocks
    hipLaunchKernelGGL(qkv_gemv_kernel, dim3(768), dim3(256), 0, stream,
                       z, Wq, Wk, Wv, Q, K, V);
    hipLaunchKernelGGL(attn_infer_kernel, dim3(NAG + ZD), dim3(256), 0, stream,
                       Q, K, V, Wi, bi, z, out, partial);
    hipLaunchKernelGGL(loss_reduce_kernel, dim3(1), dim3(64), 0, stream,
                       partial, out);
}